// Round 9
// baseline (447.024 us; speedup 1.0000x reference)
//
#include <hip/hip_runtime.h>

#define SEQ    256
#define BATCH  32
#define NT     2
#define DIM    128
#define LTAPE  256

typedef float f32x4 __attribute__((ext_vector_type(4)));
typedef short s16x8 __attribute__((ext_vector_type(8)));
typedef unsigned int u32;
typedef unsigned short u16;

__device__ __forceinline__ float sigm(float x) { return 1.f / (1.f + __expf(-x)); }
__device__ __forceinline__ float tanh_(float x) { float e = __expf(2.f * x); return 1.f - 2.f / (e + 1.f); }
__device__ __forceinline__ u16 f2bf(float x) {
  u32 u = __builtin_bit_cast(u32, x);
  u32 r = (u + 0x7fffu + ((u >> 16) & 1u)) >> 16;
  return (u16)r;
}
__device__ __forceinline__ float bf2f(u16 b) {
  u32 u = ((u32)b) << 16; return __builtin_bit_cast(float, u);
}

// ---------------------------------------------------------------------------
// bf16 MFMA GEMM (verified): C[M][N] = A[M][256] @ W[N][256]^T + bias.
// ---------------------------------------------------------------------------
template<bool A_BF16, bool OUT_BF16>
__global__ __launch_bounds__(256) void gemm_mfma(
    const void* __restrict__ Av, const float* __restrict__ W,
    const float* __restrict__ bias, void* __restrict__ Cv, int N) {
  __shared__ u16 As[128 * 40];
  __shared__ u16 Bs[64 * 40];
  const int tid = threadIdx.x;
  const int bm = blockIdx.x * 128, bn = blockIdx.y * 64;
  const int wv = tid >> 6, lane = tid & 63;
  const int wm = wv >> 1, wn = wv & 1;
  const int l15 = lane & 15, l4 = lane >> 4;
  f32x4 acc[4][2] = {};
  const int arow = tid >> 1, ahalf = tid & 1;
  const int brow = (tid & 127) >> 1, bhalf = tid & 1;

  for (int k0 = 0; k0 < 256; k0 += 32) {
    u16 abuf[16];
    if (A_BF16) {
      const u16* A = (const u16*)Av;
      const uint4* p = (const uint4*)(A + (size_t)(bm + arow) * 256 + k0 + ahalf * 16);
      *(uint4*)(abuf) = p[0]; *(uint4*)(abuf + 8) = p[1];
    } else {
      const float* A = (const float*)Av;
      const float* src = A + (size_t)(bm + arow) * 256 + k0 + ahalf * 16;
      float4 x0 = ((const float4*)src)[0], x1 = ((const float4*)src)[1];
      float4 x2 = ((const float4*)src)[2], x3 = ((const float4*)src)[3];
      float xs[16] = {x0.x, x0.y, x0.z, x0.w, x1.x, x1.y, x1.z, x1.w,
                      x2.x, x2.y, x2.z, x2.w, x3.x, x3.y, x3.z, x3.w};
#pragma unroll
      for (int j = 0; j < 16; ++j) abuf[j] = f2bf(xs[j]);
    }
    u16 bbuf[16];
    if (tid < 128) {
      const float* src = W + (size_t)(bn + brow) * 256 + k0 + bhalf * 16;
      float4 x0 = ((const float4*)src)[0], x1 = ((const float4*)src)[1];
      float4 x2 = ((const float4*)src)[2], x3 = ((const float4*)src)[3];
      float xs[16] = {x0.x, x0.y, x0.z, x0.w, x1.x, x1.y, x1.z, x1.w,
                      x2.x, x2.y, x2.z, x2.w, x3.x, x3.y, x3.z, x3.w};
#pragma unroll
      for (int j = 0; j < 16; ++j) bbuf[j] = f2bf(xs[j]);
    }
    __syncthreads();
    *(uint4*)&As[arow * 40 + ahalf * 16] = *(const uint4*)(abuf);
    *(uint4*)&As[arow * 40 + ahalf * 16 + 8] = *(const uint4*)(abuf + 8);
    if (tid < 128) {
      *(uint4*)&Bs[brow * 40 + bhalf * 16] = *(const uint4*)(bbuf);
      *(uint4*)&Bs[brow * 40 + bhalf * 16 + 8] = *(const uint4*)(bbuf + 8);
    }
    __syncthreads();
    s16x8 af[4], bfr[2];
#pragma unroll
    for (int mi = 0; mi < 4; ++mi)
      af[mi] = *(const s16x8*)&As[(wm * 64 + mi * 16 + l15) * 40 + l4 * 8];
#pragma unroll
    for (int ni = 0; ni < 2; ++ni)
      bfr[ni] = *(const s16x8*)&Bs[(wn * 32 + ni * 16 + l15) * 40 + l4 * 8];
#pragma unroll
    for (int mi = 0; mi < 4; ++mi)
#pragma unroll
      for (int ni = 0; ni < 2; ++ni)
        acc[mi][ni] = __builtin_amdgcn_mfma_f32_16x16x32_bf16(af[mi], bfr[ni], acc[mi][ni], 0, 0, 0);
  }
#pragma unroll
  for (int mi = 0; mi < 4; ++mi)
#pragma unroll
    for (int ni = 0; ni < 2; ++ni)
#pragma unroll
      for (int r = 0; r < 4; ++r) {
        int row = bm + wm * 64 + mi * 16 + l4 * 4 + r;
        int col = bn + wn * 32 + ni * 16 + l15;
        float val = acc[mi][ni][r] + bias[col];
        if (OUT_BF16) ((u16*)Cv)[(size_t)row * N + col] = f2bf(val);
        else          ((float*)Cv)[(size_t)row * N + col] = val;
      }
}

// ---------------------------------------------------------------------------
// f32 SIMT GEMM for xg (original torch gate-order columns).
// ---------------------------------------------------------------------------
__global__ __launch_bounds__(256) void gemm_nt(
    const float* __restrict__ A, const float* __restrict__ W,
    const float* __restrict__ b1, const float* __restrict__ b2,
    float* __restrict__ C, int N) {
  __shared__ float Asm[16][68];
  __shared__ float Bsm[16][68];
  const int tid = threadIdx.x;
  const int bm = blockIdx.x * 64;
  const int bn = blockIdx.y * 64;
  const int lr = tid >> 2;
  const int lc4 = (tid & 3) * 4;
  const int tm = (tid & 15) * 4;
  const int tn = (tid >> 4) * 4;
  float acc[4][4];
#pragma unroll
  for (int i = 0; i < 4; ++i)
#pragma unroll
    for (int j = 0; j < 4; ++j) acc[i][j] = 0.f;
  for (int k0 = 0; k0 < 256; k0 += 16) {
    float4 av = *reinterpret_cast<const float4*>(&A[(bm + lr) * 256 + k0 + lc4]);
    float4 bv = *reinterpret_cast<const float4*>(&W[(bn + lr) * 256 + k0 + lc4]);
    __syncthreads();
    Asm[lc4 + 0][lr] = av.x; Asm[lc4 + 1][lr] = av.y; Asm[lc4 + 2][lr] = av.z; Asm[lc4 + 3][lr] = av.w;
    Bsm[lc4 + 0][lr] = bv.x; Bsm[lc4 + 1][lr] = bv.y; Bsm[lc4 + 2][lr] = bv.z; Bsm[lc4 + 3][lr] = bv.w;
    __syncthreads();
#pragma unroll
    for (int kk = 0; kk < 16; ++kk) {
      float4 a = *reinterpret_cast<const float4*>(&Asm[kk][tm]);
      float4 b = *reinterpret_cast<const float4*>(&Bsm[kk][tn]);
      float a_[4] = {a.x, a.y, a.z, a.w};
      float b_[4] = {b.x, b.y, b.z, b.w};
#pragma unroll
      for (int i = 0; i < 4; ++i)
#pragma unroll
        for (int j = 0; j < 4; ++j) acc[i][j] += a_[i] * b_[j];
    }
  }
#pragma unroll
  for (int i = 0; i < 4; ++i)
#pragma unroll
    for (int j = 0; j < 4; ++j) {
      int n = bn + tn + j;
      float bias = b1[n] + (b2 ? b2[n] : 0.f);
      C[(size_t)(bm + tm + i) * N + n] = acc[i][j] + bias;
    }
}

// ---------------------------------------------------------------------------
// LSTM core (r8, verified): 32 blocks, 1 batch/wave, 16 W_hh regs/lane.
// ---------------------------------------------------------------------------
__global__ __launch_bounds__(64, 1) void lstm_kernel(
    const float* __restrict__ xg,    // [SEQ][32][64] torch gate order
    const float* __restrict__ W_hh,  // [64][16]
    float* __restrict__ hout) {      // [SEQ][32][16]
  const int lane = threadIdx.x;
  const int b = blockIdx.x;
  const int k = lane & 15, q = lane >> 4;
  float w[16];
#pragma unroll
  for (int kk = 0; kk < 16; ++kk) w[kk] = W_hh[lane * 16 + kk];
  float h = 0.f, c = 0.f;
  const float* xb = xg + (size_t)b * 64 + lane;
  float xA = xb[0 * 2048];
  float xB = xb[1 * 2048];
  float xC = xb[2 * 2048];
  float xD = xb[3 * 2048];

#define LSTM_STEP(S, XV)                                                     \
  {                                                                          \
    float hb[16];                                                            \
    _Pragma("unroll") for (int kk = 0; kk < 16; ++kk)                        \
      hb[kk] = __shfl(h, kk, 64);                                            \
    float pa = w[0] * hb[0], pb = w[1] * hb[1];                              \
    float pcc = w[2] * hb[2], pd = w[3] * hb[3];                             \
    _Pragma("unroll") for (int kk = 4; kk < 16; kk += 4) {                   \
      pa += w[kk + 0] * hb[kk + 0];                                         \
      pb += w[kk + 1] * hb[kk + 1];                                         \
      pcc += w[kk + 2] * hb[kk + 2];                                        \
      pd += w[kk + 3] * hb[kk + 3];                                         \
    }                                                                        \
    float g = XV + (pa + pb) + (pcc + pd);                                   \
    float gi = __shfl(g, k, 64);                                             \
    float gf = __shfl(g, 16 + k, 64);                                        \
    float gg = __shfl(g, 32 + k, 64);                                        \
    float go = __shfl(g, 48 + k, 64);                                        \
    c = sigm(gf) * c + sigm(gi) * tanh_(gg);                                 \
    h = sigm(go) * tanh_(c);                                                 \
    if (q == 0) hout[(size_t)((S) * 32 + b) * 16 + k] = h;                   \
  }

  for (int s0 = 0; s0 < SEQ; s0 += 4) {
    int p4 = s0 + 4; if (p4 > 255) p4 = 255;
    int p5 = s0 + 5; if (p5 > 255) p5 = 255;
    int p6 = s0 + 6; if (p6 > 255) p6 = 255;
    int p7 = s0 + 7; if (p7 > 255) p7 = 255;
    float nA = xb[(size_t)p4 * 2048];
    float nB = xb[(size_t)p5 * 2048];
    float nC = xb[(size_t)p6 * 2048];
    float nD = xb[(size_t)p7 * 2048];
    LSTM_STEP(s0 + 0, xA);
    LSTM_STEP(s0 + 1, xB);
    LSTM_STEP(s0 + 2, xC);
    LSTM_STEP(s0 + 3, xD);
    xA = nA; xB = nB; xC = nC; xD = nD;
  }
#undef LSTM_STEP
}

// ---------------------------------------------------------------------------
// Action heads: softmax/sigmoid from raw h -> pc[p][s][8].
// ---------------------------------------------------------------------------
__global__ __launch_bounds__(256) void head_kernel(
    const float* __restrict__ hout,  // [SEQ][32][16]
    float* __restrict__ pc) {        // [64][256][8]
  const int idx = blockIdx.x * 256 + threadIdx.x;
  const int e = idx & 7, s = (idx >> 3) & 255, p = idx >> 11;
  const int b = p >> 1, t = p & 1;
  const float* hp = hout + ((size_t)(s * 32 + b)) * 16 + t * 8;
  float outv;
  if (e < 3) {
    float a0 = hp[0], a1 = hp[1], a2 = hp[2];
    float m = fmaxf(a0, fmaxf(a1, a2));
    float e0 = __expf(a0 - m), e1 = __expf(a1 - m), e2 = __expf(a2 - m);
    float inv = 1.f / (e0 + e1 + e2);
    outv = (e == 0 ? e0 : (e == 1 ? e1 : e2)) * inv;
  } else if (e < 6) {
    float a3 = hp[3], a4 = hp[4], a5 = hp[5];
    float m = fmaxf(a3, fmaxf(a4, a5));
    float e0 = __expf(a3 - m), e1 = __expf(a4 - m), e2 = __expf(a5 - m);
    float inv = 1.f / (e0 + e1 + e2);
    outv = (e == 3 ? e0 : (e == 4 ? e1 : e2)) * inv;
  } else {
    outv = sigm(hp[e]);
  }
  pc[idx] = outv;
}

// ---------------------------------------------------------------------------
// Position precompute, 4x unrolled with 4-step coefficient prefetch from pc.
// ---------------------------------------------------------------------------
__global__ __launch_bounds__(64, 1) void pos_kernel(
    const float* __restrict__ pc,      // [64][256][8]
    float* __restrict__ posW, float* __restrict__ posRs,
    float* __restrict__ out_rpos, float* __restrict__ out_wpos) {
  const int p = blockIdx.x, lane = threadIdx.x;
  float r0 = 0, r1 = 0, r2 = 0, r3 = 0, w0 = 0, w1 = 0, w2 = 0, w3 = 0;
  if (lane == 0) { r0 = 1.f; w0 = 1.f; }
  const float* pcb = pc + (size_t)p * 2048;
  float4 c0 = *(const float4*)&pcb[0];
  float4 c1 = *(const float4*)&pcb[4];
  for (int s0 = 0; s0 < SEQ; s0 += 4) {
    float4 pf[8];
#pragma unroll
    for (int u = 0; u < 4; ++u) {
      int sn = s0 + u + 1; if (sn > 255) sn = 255;
      pf[2 * u]     = *(const float4*)&pcb[sn * 8];
      pf[2 * u + 1] = *(const float4*)&pcb[sn * 8 + 4];
    }
#pragma unroll
    for (int u = 0; u < 4; ++u) {
      const int s = s0 + u;
      size_t ob = ((size_t)p * 256 + s) * 256 + lane * 4;
      *(float4*)(posW + ob) = make_float4(w0, w1, w2, w3);
      float rw0 = c1.z;
      *(float4*)(posRs + ob) = make_float4(r0 * rw0, r1 * rw0, r2 * rw0, r3 * rw0);
      const float crd0 = c0.x, crd1 = c0.y, crd2 = c0.z;
      const float cwd0 = c0.w, cwd1 = c1.x, cwd2 = c1.y;
      float rn  = __shfl(r0, (lane + 1) & 63, 64);
      float rpv = __shfl(r3, (lane + 63) & 63, 64);
      float nw0 = r1 * cwd0 + w0 * cwd1 + rpv * cwd2;
      float nr0 = r1 * crd0 + r0 * crd1 + rpv * crd2;
      float nw1 = r2 * cwd0 + w1 * cwd1 + r0 * cwd2;
      float nr1 = r2 * crd0 + r1 * crd1 + r0 * crd2;
      float nw2 = r3 * cwd0 + w2 * cwd1 + r1 * cwd2;
      float nr2 = r3 * crd0 + r2 * crd1 + r1 * crd2;
      float nw3 = rn * cwd0 + w3 * cwd1 + r2 * cwd2;
      float nr3 = rn * crd0 + r3 * crd1 + r2 * crd2;
      r0 = nr0; r1 = nr1; r2 = nr2; r3 = nr3;
      w0 = nw0; w1 = nw1; w2 = nw2; w3 = nw3;
      c0 = pf[2 * u]; c1 = pf[2 * u + 1];
    }
  }
  out_rpos[(size_t)(lane * 4 + 0) * 64 + p] = r0;
  out_rpos[(size_t)(lane * 4 + 1) * 64 + p] = r1;
  out_rpos[(size_t)(lane * 4 + 2) * 64 + p] = r2;
  out_rpos[(size_t)(lane * 4 + 3) * 64 + p] = r3;
  out_wpos[(size_t)(lane * 4 + 0) * 64 + p] = w0;
  out_wpos[(size_t)(lane * 4 + 1) * 64 + p] = w1;
  out_wpos[(size_t)(lane * 4 + 2) * 64 + p] = w2;
  out_wpos[(size_t)(lane * 4 + 3) * 64 + p] = w3;
}

// ---------------------------------------------------------------------------
// Batched per-pair GEMM with hi/lo bf16 compensation (3 MFMA terms ~ f32).
// ---------------------------------------------------------------------------
template<bool TRANS_A, bool B_NT, int MODE, int OUTK, int BROW>
__global__ __launch_bounds__(256) void bgemm(
    const float* __restrict__ A, const float* __restrict__ B,
    const float* __restrict__ pc, float* __restrict__ C,
    size_t sA, size_t sB) {
  __shared__ u16 Ah[128 * 40], Al[128 * 40], Bh[64 * 40], Bl[64 * 40];
  const int p = blockIdx.z;
  const int bm = blockIdx.y * 128, bn = blockIdx.x * 64;
  const int tid = threadIdx.x, wv = tid >> 6, lane = tid & 63;
  const int wm = wv >> 1, wn = wv & 1, l15 = lane & 15, l4 = lane >> 4;
  const int b = p >> 1, t = p & 1;

  if (MODE == 1 && bn >= bm + 128) return;
  if (MODE == 2 && bn >= bm + 128) {
#pragma unroll
    for (int mi = 0; mi < 4; ++mi)
#pragma unroll
      for (int ni = 0; ni < 2; ++ni)
#pragma unroll
        for (int r = 0; r < 4; ++r) {
          int row = bm + wm * 64 + mi * 16 + l4 * 4 + r;
          int col = bn + wn * 32 + ni * 16 + l15;
          C[(size_t)p * 65536 + (size_t)row * 256 + col] = 0.f;
        }
    return;
  }

  const float* Ap = A + (size_t)p * sA;
  const float* Bp = B + (size_t)p * sB;
  f32x4 acc[4][2] = {};

  for (int k0 = 0; k0 < 256; k0 += 32) {
    float xa[16];
    if (!TRANS_A) {
      const int m = tid >> 1, kq = (tid & 1) * 16;
      const float* src = Ap + (size_t)(bm + m) * 256 + k0 + kq;
#pragma unroll
      for (int j = 0; j < 4; ++j) *(float4*)(xa + j * 4) = ((const float4*)src)[j];
    } else {
      const int kr = tid >> 3, mq = (tid & 7) * 16;
      const float* src = Ap + (size_t)(k0 + kr) * 256 + bm + mq;
#pragma unroll
      for (int j = 0; j < 4; ++j) *(float4*)(xa + j * 4) = ((const float4*)src)[j];
    }
    u16 ah[16], al[16];
#pragma unroll
    for (int j = 0; j < 16; ++j) {
      u16 hh = f2bf(xa[j]);
      ah[j] = hh; al[j] = f2bf(xa[j] - bf2f(hh));
    }
    float xb[8];
    if (B_NT) {
      const int n = tid >> 2, kq = (tid & 3) * 8;
      const float* src = Bp + (size_t)(bn + n) * 256 + k0 + kq;
      *(float4*)(xb) = ((const float4*)src)[0];
      *(float4*)(xb + 4) = ((const float4*)src)[1];
    } else {
      const int kr = tid >> 3, nq = (tid & 7) * 8;
      const float* src = Bp + (size_t)(k0 + kr) * BROW + bn + nq;
      *(float4*)(xb) = ((const float4*)src)[0];
      *(float4*)(xb + 4) = ((const float4*)src)[1];
    }
    u16 bh[8], bl[8];
#pragma unroll
    for (int j = 0; j < 8; ++j) {
      u16 hh = f2bf(xb[j]);
      bh[j] = hh; bl[j] = f2bf(xb[j] - bf2f(hh));
    }
    __syncthreads();
    if (!TRANS_A) {
      const int m = tid >> 1, kq = (tid & 1) * 16;
      *(uint4*)&Ah[m * 40 + kq]     = *(const uint4*)(ah);
      *(uint4*)&Ah[m * 40 + kq + 8] = *(const uint4*)(ah + 8);
      *(uint4*)&Al[m * 40 + kq]     = *(const uint4*)(al);
      *(uint4*)&Al[m * 40 + kq + 8] = *(const uint4*)(al + 8);
    } else {
      const int kr = tid >> 3, mq = (tid & 7) * 16;
#pragma unroll
      for (int j = 0; j < 16; ++j) {
        Ah[(mq + j) * 40 + kr] = ah[j];
        Al[(mq + j) * 40 + kr] = al[j];
      }
    }
    if (B_NT) {
      const int n = tid >> 2, kq = (tid & 3) * 8;
      *(uint4*)&Bh[n * 40 + kq] = *(const uint4*)(bh);
      *(uint4*)&Bl[n * 40 + kq] = *(const uint4*)(bl);
    } else {
      const int kr = tid >> 3, nq = (tid & 7) * 8;
#pragma unroll
      for (int j = 0; j < 8; ++j) {
        Bh[(nq + j) * 40 + kr] = bh[j];
        Bl[(nq + j) * 40 + kr] = bl[j];
      }
    }
    __syncthreads();
    s16x8 fah[4], fal[4], fbh[2], fbl[2];
#pragma unroll
    for (int mi = 0; mi < 4; ++mi) {
      fah[mi] = *(const s16x8*)&Ah[(wm * 64 + mi * 16 + l15) * 40 + l4 * 8];
      fal[mi] = *(const s16x8*)&Al[(wm * 64 + mi * 16 + l15) * 40 + l4 * 8];
    }
#pragma unroll
    for (int ni = 0; ni < 2; ++ni) {
      fbh[ni] = *(const s16x8*)&Bh[(wn * 32 + ni * 16 + l15) * 40 + l4 * 8];
      fbl[ni] = *(const s16x8*)&Bl[(wn * 32 + ni * 16 + l15) * 40 + l4 * 8];
    }
#pragma unroll
    for (int mi = 0; mi < 4; ++mi)
#pragma unroll
      for (int ni = 0; ni < 2; ++ni) {
        acc[mi][ni] = __builtin_amdgcn_mfma_f32_16x16x32_bf16(fah[mi], fbh[ni], acc[mi][ni], 0, 0, 0);
        acc[mi][ni] = __builtin_amdgcn_mfma_f32_16x16x32_bf16(fah[mi], fbl[ni], acc[mi][ni], 0, 0, 0);
        acc[mi][ni] = __builtin_amdgcn_mfma_f32_16x16x32_bf16(fal[mi], fbh[ni], acc[mi][ni], 0, 0, 0);
      }
  }
#pragma unroll
  for (int mi = 0; mi < 4; ++mi)
#pragma unroll
    for (int ni = 0; ni < 2; ++ni)
#pragma unroll
      for (int r = 0; r < 4; ++r) {
        int row = bm + wm * 64 + mi * 16 + l4 * 4 + r;
        int col = bn + wn * 32 + ni * 16 + l15;
        float v = acc[mi][ni][r];
        if (MODE == 1) v = (col < row) ? v * pc[((size_t)p * 256 + row) * 8 + 7] : 0.f;
        if (MODE == 2) v = (col <= row) ? v : 0.f;
        if (OUTK == 0)      C[(size_t)p * 65536 + (size_t)row * 256 + col] = v;
        else if (OUTK == 1) C[((size_t)(row * 32 + b)) * 256 + t * 128 + col] = v;
        else                C[((size_t)row * 64 + p) * 128 + col] = v;
      }
}

// ---------------------------------------------------------------------------
// Blocked triangular solve (I + L) delta = rw1 * v.  Grid 128 = (pair, chalf).
// r9: off-diag L tile staged into LDS (coalesced float4) -- r8 was latency-
// bound on 8 wave-uniform 4B global loads per j (VALUBusy 9%, 264K cyc/blk).
// Lt row stride 232 floats: staging writes land 2-way bank-aliased (free);
// off-diag reads are wave-uniform (broadcast) + lane-spread ds (2/bank).
// ---------------------------------------------------------------------------
__global__ __launch_bounds__(256) void solve_kernel(
    const float* __restrict__ L,        // [64][256][256] strict-lower, rw1-scaled
    const u16* __restrict__ values,     // bf16 [8192][256]
    const float* __restrict__ pc,       // [64][256][8]
    float* __restrict__ delta) {        // [64][256][128]
  const int p = blockIdx.x >> 1, half = blockIdx.x & 1;
  const int b = p >> 1, t = p & 1;
  const int tid = threadIdx.x, w = tid >> 6, lane = tid & 63;
  __shared__ float ds[256][64];   // 64 KB: solved delta columns
  __shared__ float Lt[32][232];   // 29 KB: staged L tile (rows s0..s0+31, cols<s0)
  __shared__ float Ps[32][64];    //  8 KB
  __shared__ float Db[32][33];    //  4 KB
  const float* Lp = L + (size_t)p * 65536;
  const int sr = tid >> 3, seg = tid & 7;   // staging: row, column-segment

  for (int k = 0; k < 8; ++k) {
    const int s0 = k * 32;
    // ---- stage diagonal 32x32 tile ----
    {
      float4 dv = *(const float4*)(Lp + (size_t)(s0 + sr) * 256 + s0 + seg * 4);
      Db[sr][seg * 4 + 0] = dv.x; Db[sr][seg * 4 + 1] = dv.y;
      Db[sr][seg * 4 + 2] = dv.z; Db[sr][seg * 4 + 3] = dv.w;
    }
    // ---- stage off-diag L tile: rows s0+sr, cols [0, s0), coalesced ----
    for (int c4 = seg; c4 < (s0 >> 2); c4 += 8) {
      float4 lv = *(const float4*)(Lp + (size_t)(s0 + sr) * 256 + c4 * 4);
      *(float4*)&Lt[sr][c4 * 4] = lv;
    }
    // ---- b init (global loads overlap staging) ----
    float acc[8];
#pragma unroll
    for (int i = 0; i < 8; ++i) {
      const int s = s0 + w * 8 + i;
      float rv = bf2f(values[((size_t)(s * 32 + b)) * 256 + t * 128 + half * 64 + lane]);
      acc[i] = rv * pc[((size_t)p * 256 + s) * 8 + 7];
    }
    __syncthreads();  // Lt/Db staged; ds from previous diag visible
    // ---- off-diag: acc[i] -= sum_{j<s0} Lt[w*8+i][j] * ds[j][lane] ----
    const int row0 = w * 8;
    for (int j = 0; j < s0; j += 4) {
      float dj0 = ds[j + 0][lane];
      float dj1 = ds[j + 1][lane];
      float dj2 = ds[j + 2][lane];
      float dj3 = ds[j + 3][lane];
#pragma unroll
      for (int i = 0; i < 8; ++i) {
        float4 lv = *(const float4*)&Lt[row0 + i][j];
        acc[i] -= lv.x * dj0;
        acc[i] -= lv.y * dj1;
        acc[i] -= lv.z * dj2;
        acc[i] -= lv.w * dj3;
      }
    }
#pragma unroll
    for (int i = 0; i < 8; ++i) Ps[w * 8 + i][lane] = acc[i];
    __syncthreads();
    // ---- serial diagonal solve (wave 0) ----
    if (w == 0) {
      float d[32];
#pragma unroll
      for (int r = 0; r < 32; ++r) {
        float xa = Ps[r][lane], xb = 0.f;
#pragma unroll
        for (int q = 0; q < 32; ++q) {
          if (q < r) {
            if (q & 1) xb -= Db[r][q] * d[q];
            else       xa -= Db[r][q] * d[q];
          }
        }
        float x = xa + xb;
        d[r] = x;
        ds[s0 + r][lane] = x;
        delta[((size_t)p * 256 + s0 + r) * 128 + half * 64 + lane] = x;
      }
    }
    __syncthreads();
  }
}

// ---------------------------------------------------------------------------
extern "C" void kernel_launch(void* const* d_in, const int* in_sizes, int n_in,
                              void* d_out, int out_size, void* d_ws, size_t ws_size,
                              hipStream_t stream) {
  const float* inputs = (const float*)d_in[0];
  const float* W_ih = (const float*)d_in[2];
  const float* W_hh = (const float*)d_in[3];
  const float* b_ih = (const float*)d_in[4];
  const float* b_hh = (const float*)d_in[5];
  const float* W_val = (const float*)d_in[6];
  const float* b_val = (const float*)d_in[7];
  const float* W_out = (const float*)d_in[8];
  const float* b_out = (const float*)d_in[9];

  float* out = (float*)d_out;
  float* out_tape = out + 2097152;
  float* out_rpos = out + 4194304;
  float* out_wpos = out + 4210688;

  char* ws = (char*)d_ws;
  float* posW      = (float*)(ws);                    // 16 MB  [64][256][256]
  float* posRs     = (float*)(ws + 16777216);         // 16 MB  (reused: reads_f32)
  float* LHm       = (float*)(ws + 33554432);         // 16 MB  (L, then Hm)
  u16*   values_bf = (u16*)  (ws + 50331648);         //  4 MB
  float* xg        = (float*)(ws + 54525952);         //  2 MB (dead after lstm)
  float* delta     = (float*)(ws + 54525952);         //  8 MB (aliases xg)
  float* pcb       = (float*)(ws + 62914560);         // 512 KB [64][256][8]
  float* hout      = (float*)(ws + 63438848);         // 512 KB [256][32][16]
  float* reads_f32 = posRs;

  // 1. values (bf16) = inputs @ W_val^T + b_val
  gemm_mfma<false, true><<<dim3(64, 4), 256, 0, stream>>>(inputs, W_val, b_val, values_bf, 256);
  // 2. xg (f32) = inputs @ W_ih^T + (b_ih + b_hh)
  gemm_nt<<<dim3(128, 1), 256, 0, stream>>>(inputs, W_ih, b_ih, b_hh, xg, 64);
  // 3. LSTM core -> raw h
  lstm_kernel<<<32, 64, 0, stream>>>(xg, W_hh, hout);
  // 3b. action heads -> packed coefficients pc
  head_kernel<<<512, 256, 0, stream>>>(hout, pcb);
  // 4. position trajectories
  pos_kernel<<<64, 64, 0, stream>>>(pcb, posW, posRs, out_rpos, out_wpos);
  // 5. L = rw1 (.) strict_tril(posW posW^T)
  bgemm<false, true, 1, 0, 256><<<dim3(4, 2, 64), 256, 0, stream>>>(
      posW, posW, pcb, LHm, 65536, 65536);
  // 6. blocked triangular solve -> delta
  solve_kernel<<<128, 256, 0, stream>>>(LHm, values_bf, pcb, delta);
  // 7. Hm = tril_incl(posRs posW^T)   (overwrites L)
  bgemm<false, true, 2, 0, 256><<<dim3(4, 2, 64), 256, 0, stream>>>(
      posRs, posW, pcb, LHm, 65536, 65536);
  // 8. reads = Hm @ delta   (reads layout [s*32+b][256])
  bgemm<false, false, 0, 1, 128><<<dim3(2, 2, 64), 256, 0, stream>>>(
      LHm, delta, pcb, reads_f32, 65536, 32768);
  // 9. out_tape = posW^T @ delta
  bgemm<true, false, 0, 2, 128><<<dim3(2, 2, 64), 256, 0, stream>>>(
      posW, delta, pcb, out_tape, 65536, 32768);
  // 10. outputs = reads @ W_out^T + b_out
  gemm_mfma<false, false><<<dim3(64, 4), 256, 0, stream>>>(reads_f32, W_out, b_out, out, 256);
}

// Round 10
// 380.800 us; speedup vs baseline: 1.1739x; 1.1739x over previous
//
#include <hip/hip_runtime.h>

#define SEQ    256
#define BATCH  32
#define NT     2
#define DIM    128
#define LTAPE  256

typedef float f32x4 __attribute__((ext_vector_type(4)));
typedef short s16x8 __attribute__((ext_vector_type(8)));
typedef unsigned int u32;
typedef unsigned short u16;

__device__ __forceinline__ float sigm(float x) { return 1.f / (1.f + __expf(-x)); }
__device__ __forceinline__ float tanh_(float x) { float e = __expf(2.f * x); return 1.f - 2.f / (e + 1.f); }
__device__ __forceinline__ u16 f2bf(float x) {
  u32 u = __builtin_bit_cast(u32, x);
  u32 r = (u + 0x7fffu + ((u >> 16) & 1u)) >> 16;
  return (u16)r;
}
__device__ __forceinline__ float bf2f(u16 b) {
  u32 u = ((u32)b) << 16; return __builtin_bit_cast(float, u);
}

// ---------------------------------------------------------------------------
// bf16 MFMA GEMM (verified): C[M][N] = A[M][256] @ W[N][256]^T + bias.
// ---------------------------------------------------------------------------
template<bool A_BF16, bool OUT_BF16>
__global__ __launch_bounds__(256) void gemm_mfma(
    const void* __restrict__ Av, const float* __restrict__ W,
    const float* __restrict__ bias, void* __restrict__ Cv, int N) {
  __shared__ u16 As[128 * 40];
  __shared__ u16 Bs[64 * 40];
  const int tid = threadIdx.x;
  const int bm = blockIdx.x * 128, bn = blockIdx.y * 64;
  const int wv = tid >> 6, lane = tid & 63;
  const int wm = wv >> 1, wn = wv & 1;
  const int l15 = lane & 15, l4 = lane >> 4;
  f32x4 acc[4][2] = {};
  const int arow = tid >> 1, ahalf = tid & 1;
  const int brow = (tid & 127) >> 1, bhalf = tid & 1;

  for (int k0 = 0; k0 < 256; k0 += 32) {
    u16 abuf[16];
    if (A_BF16) {
      const u16* A = (const u16*)Av;
      const uint4* p = (const uint4*)(A + (size_t)(bm + arow) * 256 + k0 + ahalf * 16);
      *(uint4*)(abuf) = p[0]; *(uint4*)(abuf + 8) = p[1];
    } else {
      const float* A = (const float*)Av;
      const float* src = A + (size_t)(bm + arow) * 256 + k0 + ahalf * 16;
      float4 x0 = ((const float4*)src)[0], x1 = ((const float4*)src)[1];
      float4 x2 = ((const float4*)src)[2], x3 = ((const float4*)src)[3];
      float xs[16] = {x0.x, x0.y, x0.z, x0.w, x1.x, x1.y, x1.z, x1.w,
                      x2.x, x2.y, x2.z, x2.w, x3.x, x3.y, x3.z, x3.w};
#pragma unroll
      for (int j = 0; j < 16; ++j) abuf[j] = f2bf(xs[j]);
    }
    u16 bbuf[16];
    if (tid < 128) {
      const float* src = W + (size_t)(bn + brow) * 256 + k0 + bhalf * 16;
      float4 x0 = ((const float4*)src)[0], x1 = ((const float4*)src)[1];
      float4 x2 = ((const float4*)src)[2], x3 = ((const float4*)src)[3];
      float xs[16] = {x0.x, x0.y, x0.z, x0.w, x1.x, x1.y, x1.z, x1.w,
                      x2.x, x2.y, x2.z, x2.w, x3.x, x3.y, x3.z, x3.w};
#pragma unroll
      for (int j = 0; j < 16; ++j) bbuf[j] = f2bf(xs[j]);
    }
    __syncthreads();
    *(uint4*)&As[arow * 40 + ahalf * 16] = *(const uint4*)(abuf);
    *(uint4*)&As[arow * 40 + ahalf * 16 + 8] = *(const uint4*)(abuf + 8);
    if (tid < 128) {
      *(uint4*)&Bs[brow * 40 + bhalf * 16] = *(const uint4*)(bbuf);
      *(uint4*)&Bs[brow * 40 + bhalf * 16 + 8] = *(const uint4*)(bbuf + 8);
    }
    __syncthreads();
    s16x8 af[4], bfr[2];
#pragma unroll
    for (int mi = 0; mi < 4; ++mi)
      af[mi] = *(const s16x8*)&As[(wm * 64 + mi * 16 + l15) * 40 + l4 * 8];
#pragma unroll
    for (int ni = 0; ni < 2; ++ni)
      bfr[ni] = *(const s16x8*)&Bs[(wn * 32 + ni * 16 + l15) * 40 + l4 * 8];
#pragma unroll
    for (int mi = 0; mi < 4; ++mi)
#pragma unroll
      for (int ni = 0; ni < 2; ++ni)
        acc[mi][ni] = __builtin_amdgcn_mfma_f32_16x16x32_bf16(af[mi], bfr[ni], acc[mi][ni], 0, 0, 0);
  }
#pragma unroll
  for (int mi = 0; mi < 4; ++mi)
#pragma unroll
    for (int ni = 0; ni < 2; ++ni)
#pragma unroll
      for (int r = 0; r < 4; ++r) {
        int row = bm + wm * 64 + mi * 16 + l4 * 4 + r;
        int col = bn + wn * 32 + ni * 16 + l15;
        float val = acc[mi][ni][r] + bias[col];
        if (OUT_BF16) ((u16*)Cv)[(size_t)row * N + col] = f2bf(val);
        else          ((float*)Cv)[(size_t)row * N + col] = val;
      }
}

// ---------------------------------------------------------------------------
// f32 SIMT GEMM for xg (original torch gate-order columns).
// ---------------------------------------------------------------------------
__global__ __launch_bounds__(256) void gemm_nt(
    const float* __restrict__ A, const float* __restrict__ W,
    const float* __restrict__ b1, const float* __restrict__ b2,
    float* __restrict__ C, int N) {
  __shared__ float Asm[16][68];
  __shared__ float Bsm[16][68];
  const int tid = threadIdx.x;
  const int bm = blockIdx.x * 64;
  const int bn = blockIdx.y * 64;
  const int lr = tid >> 2;
  const int lc4 = (tid & 3) * 4;
  const int tm = (tid & 15) * 4;
  const int tn = (tid >> 4) * 4;
  float acc[4][4];
#pragma unroll
  for (int i = 0; i < 4; ++i)
#pragma unroll
    for (int j = 0; j < 4; ++j) acc[i][j] = 0.f;
  for (int k0 = 0; k0 < 256; k0 += 16) {
    float4 av = *reinterpret_cast<const float4*>(&A[(bm + lr) * 256 + k0 + lc4]);
    float4 bv = *reinterpret_cast<const float4*>(&W[(bn + lr) * 256 + k0 + lc4]);
    __syncthreads();
    Asm[lc4 + 0][lr] = av.x; Asm[lc4 + 1][lr] = av.y; Asm[lc4 + 2][lr] = av.z; Asm[lc4 + 3][lr] = av.w;
    Bsm[lc4 + 0][lr] = bv.x; Bsm[lc4 + 1][lr] = bv.y; Bsm[lc4 + 2][lr] = bv.z; Bsm[lc4 + 3][lr] = bv.w;
    __syncthreads();
#pragma unroll
    for (int kk = 0; kk < 16; ++kk) {
      float4 a = *reinterpret_cast<const float4*>(&Asm[kk][tm]);
      float4 b = *reinterpret_cast<const float4*>(&Bsm[kk][tn]);
      float a_[4] = {a.x, a.y, a.z, a.w};
      float b_[4] = {b.x, b.y, b.z, b.w};
#pragma unroll
      for (int i = 0; i < 4; ++i)
#pragma unroll
        for (int j = 0; j < 4; ++j) acc[i][j] += a_[i] * b_[j];
    }
  }
#pragma unroll
  for (int i = 0; i < 4; ++i)
#pragma unroll
    for (int j = 0; j < 4; ++j) {
      int n = bn + tn + j;
      float bias = b1[n] + (b2 ? b2[n] : 0.f);
      C[(size_t)(bm + tm + i) * N + n] = acc[i][j] + bias;
    }
}

// ---------------------------------------------------------------------------
// LSTM core (r8, verified): 32 blocks, 1 batch/wave, 16 W_hh regs/lane.
// ---------------------------------------------------------------------------
__global__ __launch_bounds__(64, 1) void lstm_kernel(
    const float* __restrict__ xg,    // [SEQ][32][64] torch gate order
    const float* __restrict__ W_hh,  // [64][16]
    float* __restrict__ hout) {      // [SEQ][32][16]
  const int lane = threadIdx.x;
  const int b = blockIdx.x;
  const int k = lane & 15, q = lane >> 4;
  float w[16];
#pragma unroll
  for (int kk = 0; kk < 16; ++kk) w[kk] = W_hh[lane * 16 + kk];
  float h = 0.f, c = 0.f;
  const float* xb = xg + (size_t)b * 64 + lane;
  float xA = xb[0 * 2048];
  float xB = xb[1 * 2048];
  float xC = xb[2 * 2048];
  float xD = xb[3 * 2048];

#define LSTM_STEP(S, XV)                                                     \
  {                                                                          \
    float hb[16];                                                            \
    _Pragma("unroll") for (int kk = 0; kk < 16; ++kk)                        \
      hb[kk] = __shfl(h, kk, 64);                                            \
    float pa = w[0] * hb[0], pb = w[1] * hb[1];                              \
    float pcc = w[2] * hb[2], pd = w[3] * hb[3];                             \
    _Pragma("unroll") for (int kk = 4; kk < 16; kk += 4) {                   \
      pa += w[kk + 0] * hb[kk + 0];                                         \
      pb += w[kk + 1] * hb[kk + 1];                                         \
      pcc += w[kk + 2] * hb[kk + 2];                                        \
      pd += w[kk + 3] * hb[kk + 3];                                         \
    }                                                                        \
    float g = XV + (pa + pb) + (pcc + pd);                                   \
    float gi = __shfl(g, k, 64);                                             \
    float gf = __shfl(g, 16 + k, 64);                                        \
    float gg = __shfl(g, 32 + k, 64);                                        \
    float go = __shfl(g, 48 + k, 64);                                        \
    c = sigm(gf) * c + sigm(gi) * tanh_(gg);                                 \
    h = sigm(go) * tanh_(c);                                                 \
    if (q == 0) hout[(size_t)((S) * 32 + b) * 16 + k] = h;                   \
  }

  for (int s0 = 0; s0 < SEQ; s0 += 4) {
    int p4 = s0 + 4; if (p4 > 255) p4 = 255;
    int p5 = s0 + 5; if (p5 > 255) p5 = 255;
    int p6 = s0 + 6; if (p6 > 255) p6 = 255;
    int p7 = s0 + 7; if (p7 > 255) p7 = 255;
    float nA = xb[(size_t)p4 * 2048];
    float nB = xb[(size_t)p5 * 2048];
    float nC = xb[(size_t)p6 * 2048];
    float nD = xb[(size_t)p7 * 2048];
    LSTM_STEP(s0 + 0, xA);
    LSTM_STEP(s0 + 1, xB);
    LSTM_STEP(s0 + 2, xC);
    LSTM_STEP(s0 + 3, xD);
    xA = nA; xB = nB; xC = nC; xD = nD;
  }
#undef LSTM_STEP
}

// ---------------------------------------------------------------------------
// Action heads: softmax/sigmoid from raw h -> pc[p][s][8].
// ---------------------------------------------------------------------------
__global__ __launch_bounds__(256) void head_kernel(
    const float* __restrict__ hout,  // [SEQ][32][16]
    float* __restrict__ pc) {        // [64][256][8]
  const int idx = blockIdx.x * 256 + threadIdx.x;
  const int e = idx & 7, s = (idx >> 3) & 255, p = idx >> 11;
  const int b = p >> 1, t = p & 1;
  const float* hp = hout + ((size_t)(s * 32 + b)) * 16 + t * 8;
  float outv;
  if (e < 3) {
    float a0 = hp[0], a1 = hp[1], a2 = hp[2];
    float m = fmaxf(a0, fmaxf(a1, a2));
    float e0 = __expf(a0 - m), e1 = __expf(a1 - m), e2 = __expf(a2 - m);
    float inv = 1.f / (e0 + e1 + e2);
    outv = (e == 0 ? e0 : (e == 1 ? e1 : e2)) * inv;
  } else if (e < 6) {
    float a3 = hp[3], a4 = hp[4], a5 = hp[5];
    float m = fmaxf(a3, fmaxf(a4, a5));
    float e0 = __expf(a3 - m), e1 = __expf(a4 - m), e2 = __expf(a5 - m);
    float inv = 1.f / (e0 + e1 + e2);
    outv = (e == 3 ? e0 : (e == 4 ? e1 : e2)) * inv;
  } else {
    outv = sigm(hp[e]);
  }
  pc[idx] = outv;
}

// ---------------------------------------------------------------------------
// Position precompute, 4x unrolled with 4-step coefficient prefetch from pc.
// ---------------------------------------------------------------------------
__global__ __launch_bounds__(64, 1) void pos_kernel(
    const float* __restrict__ pc,      // [64][256][8]
    float* __restrict__ posW, float* __restrict__ posRs,
    float* __restrict__ out_rpos, float* __restrict__ out_wpos) {
  const int p = blockIdx.x, lane = threadIdx.x;
  float r0 = 0, r1 = 0, r2 = 0, r3 = 0, w0 = 0, w1 = 0, w2 = 0, w3 = 0;
  if (lane == 0) { r0 = 1.f; w0 = 1.f; }
  const float* pcb = pc + (size_t)p * 2048;
  float4 c0 = *(const float4*)&pcb[0];
  float4 c1 = *(const float4*)&pcb[4];
  for (int s0 = 0; s0 < SEQ; s0 += 4) {
    float4 pf[8];
#pragma unroll
    for (int u = 0; u < 4; ++u) {
      int sn = s0 + u + 1; if (sn > 255) sn = 255;
      pf[2 * u]     = *(const float4*)&pcb[sn * 8];
      pf[2 * u + 1] = *(const float4*)&pcb[sn * 8 + 4];
    }
#pragma unroll
    for (int u = 0; u < 4; ++u) {
      const int s = s0 + u;
      size_t ob = ((size_t)p * 256 + s) * 256 + lane * 4;
      *(float4*)(posW + ob) = make_float4(w0, w1, w2, w3);
      float rw0 = c1.z;
      *(float4*)(posRs + ob) = make_float4(r0 * rw0, r1 * rw0, r2 * rw0, r3 * rw0);
      const float crd0 = c0.x, crd1 = c0.y, crd2 = c0.z;
      const float cwd0 = c0.w, cwd1 = c1.x, cwd2 = c1.y;
      float rn  = __shfl(r0, (lane + 1) & 63, 64);
      float rpv = __shfl(r3, (lane + 63) & 63, 64);
      float nw0 = r1 * cwd0 + w0 * cwd1 + rpv * cwd2;
      float nr0 = r1 * crd0 + r0 * crd1 + rpv * crd2;
      float nw1 = r2 * cwd0 + w1 * cwd1 + r0 * cwd2;
      float nr1 = r2 * crd0 + r1 * crd1 + r0 * crd2;
      float nw2 = r3 * cwd0 + w2 * cwd1 + r1 * cwd2;
      float nr2 = r3 * crd0 + r2 * crd1 + r1 * crd2;
      float nw3 = rn * cwd0 + w3 * cwd1 + r2 * cwd2;
      float nr3 = rn * crd0 + r3 * crd1 + r2 * crd2;
      r0 = nr0; r1 = nr1; r2 = nr2; r3 = nr3;
      w0 = nw0; w1 = nw1; w2 = nw2; w3 = nw3;
      c0 = pf[2 * u]; c1 = pf[2 * u + 1];
    }
  }
  out_rpos[(size_t)(lane * 4 + 0) * 64 + p] = r0;
  out_rpos[(size_t)(lane * 4 + 1) * 64 + p] = r1;
  out_rpos[(size_t)(lane * 4 + 2) * 64 + p] = r2;
  out_rpos[(size_t)(lane * 4 + 3) * 64 + p] = r3;
  out_wpos[(size_t)(lane * 4 + 0) * 64 + p] = w0;
  out_wpos[(size_t)(lane * 4 + 1) * 64 + p] = w1;
  out_wpos[(size_t)(lane * 4 + 2) * 64 + p] = w2;
  out_wpos[(size_t)(lane * 4 + 3) * 64 + p] = w3;
}

// ---------------------------------------------------------------------------
// Batched per-pair GEMM with hi/lo bf16 compensation (3 MFMA terms ~ f32).
// ---------------------------------------------------------------------------
template<bool TRANS_A, bool B_NT, int MODE, int OUTK, int BROW>
__global__ __launch_bounds__(256) void bgemm(
    const float* __restrict__ A, const float* __restrict__ B,
    const float* __restrict__ pc, float* __restrict__ C,
    size_t sA, size_t sB) {
  __shared__ u16 Ah[128 * 40], Al[128 * 40], Bh[64 * 40], Bl[64 * 40];
  const int p = blockIdx.z;
  const int bm = blockIdx.y * 128, bn = blockIdx.x * 64;
  const int tid = threadIdx.x, wv = tid >> 6, lane = tid & 63;
  const int wm = wv >> 1, wn = wv & 1, l15 = lane & 15, l4 = lane >> 4;
  const int b = p >> 1, t = p & 1;

  if (MODE == 1 && bn >= bm + 128) return;
  if (MODE == 2 && bn >= bm + 128) {
#pragma unroll
    for (int mi = 0; mi < 4; ++mi)
#pragma unroll
      for (int ni = 0; ni < 2; ++ni)
#pragma unroll
        for (int r = 0; r < 4; ++r) {
          int row = bm + wm * 64 + mi * 16 + l4 * 4 + r;
          int col = bn + wn * 32 + ni * 16 + l15;
          C[(size_t)p * 65536 + (size_t)row * 256 + col] = 0.f;
        }
    return;
  }

  const float* Ap = A + (size_t)p * sA;
  const float* Bp = B + (size_t)p * sB;
  f32x4 acc[4][2] = {};

  for (int k0 = 0; k0 < 256; k0 += 32) {
    float xa[16];
    if (!TRANS_A) {
      const int m = tid >> 1, kq = (tid & 1) * 16;
      const float* src = Ap + (size_t)(bm + m) * 256 + k0 + kq;
#pragma unroll
      for (int j = 0; j < 4; ++j) *(float4*)(xa + j * 4) = ((const float4*)src)[j];
    } else {
      const int kr = tid >> 3, mq = (tid & 7) * 16;
      const float* src = Ap + (size_t)(k0 + kr) * 256 + bm + mq;
#pragma unroll
      for (int j = 0; j < 4; ++j) *(float4*)(xa + j * 4) = ((const float4*)src)[j];
    }
    u16 ah[16], al[16];
#pragma unroll
    for (int j = 0; j < 16; ++j) {
      u16 hh = f2bf(xa[j]);
      ah[j] = hh; al[j] = f2bf(xa[j] - bf2f(hh));
    }
    float xb[8];
    if (B_NT) {
      const int n = tid >> 2, kq = (tid & 3) * 8;
      const float* src = Bp + (size_t)(bn + n) * 256 + k0 + kq;
      *(float4*)(xb) = ((const float4*)src)[0];
      *(float4*)(xb + 4) = ((const float4*)src)[1];
    } else {
      const int kr = tid >> 3, nq = (tid & 7) * 8;
      const float* src = Bp + (size_t)(k0 + kr) * BROW + bn + nq;
      *(float4*)(xb) = ((const float4*)src)[0];
      *(float4*)(xb + 4) = ((const float4*)src)[1];
    }
    u16 bh[8], bl[8];
#pragma unroll
    for (int j = 0; j < 8; ++j) {
      u16 hh = f2bf(xb[j]);
      bh[j] = hh; bl[j] = f2bf(xb[j] - bf2f(hh));
    }
    __syncthreads();
    if (!TRANS_A) {
      const int m = tid >> 1, kq = (tid & 1) * 16;
      *(uint4*)&Ah[m * 40 + kq]     = *(const uint4*)(ah);
      *(uint4*)&Ah[m * 40 + kq + 8] = *(const uint4*)(ah + 8);
      *(uint4*)&Al[m * 40 + kq]     = *(const uint4*)(al);
      *(uint4*)&Al[m * 40 + kq + 8] = *(const uint4*)(al + 8);
    } else {
      const int kr = tid >> 3, mq = (tid & 7) * 16;
#pragma unroll
      for (int j = 0; j < 16; ++j) {
        Ah[(mq + j) * 40 + kr] = ah[j];
        Al[(mq + j) * 40 + kr] = al[j];
      }
    }
    if (B_NT) {
      const int n = tid >> 2, kq = (tid & 3) * 8;
      *(uint4*)&Bh[n * 40 + kq] = *(const uint4*)(bh);
      *(uint4*)&Bl[n * 40 + kq] = *(const uint4*)(bl);
    } else {
      const int kr = tid >> 3, nq = (tid & 7) * 8;
#pragma unroll
      for (int j = 0; j < 8; ++j) {
        Bh[(nq + j) * 40 + kr] = bh[j];
        Bl[(nq + j) * 40 + kr] = bl[j];
      }
    }
    __syncthreads();
    s16x8 fah[4], fal[4], fbh[2], fbl[2];
#pragma unroll
    for (int mi = 0; mi < 4; ++mi) {
      fah[mi] = *(const s16x8*)&Ah[(wm * 64 + mi * 16 + l15) * 40 + l4 * 8];
      fal[mi] = *(const s16x8*)&Al[(wm * 64 + mi * 16 + l15) * 40 + l4 * 8];
    }
#pragma unroll
    for (int ni = 0; ni < 2; ++ni) {
      fbh[ni] = *(const s16x8*)&Bh[(wn * 32 + ni * 16 + l15) * 40 + l4 * 8];
      fbl[ni] = *(const s16x8*)&Bl[(wn * 32 + ni * 16 + l15) * 40 + l4 * 8];
    }
#pragma unroll
    for (int mi = 0; mi < 4; ++mi)
#pragma unroll
      for (int ni = 0; ni < 2; ++ni) {
        acc[mi][ni] = __builtin_amdgcn_mfma_f32_16x16x32_bf16(fah[mi], fbh[ni], acc[mi][ni], 0, 0, 0);
        acc[mi][ni] = __builtin_amdgcn_mfma_f32_16x16x32_bf16(fah[mi], fbl[ni], acc[mi][ni], 0, 0, 0);
        acc[mi][ni] = __builtin_amdgcn_mfma_f32_16x16x32_bf16(fal[mi], fbh[ni], acc[mi][ni], 0, 0, 0);
      }
  }
#pragma unroll
  for (int mi = 0; mi < 4; ++mi)
#pragma unroll
    for (int ni = 0; ni < 2; ++ni)
#pragma unroll
      for (int r = 0; r < 4; ++r) {
        int row = bm + wm * 64 + mi * 16 + l4 * 4 + r;
        int col = bn + wn * 32 + ni * 16 + l15;
        float v = acc[mi][ni][r];
        if (MODE == 1) v = (col < row) ? v * pc[((size_t)p * 256 + row) * 8 + 7] : 0.f;
        if (MODE == 2) v = (col <= row) ? v : 0.f;
        if (OUTK == 0)      C[(size_t)p * 65536 + (size_t)row * 256 + col] = v;
        else if (OUTK == 1) C[((size_t)(row * 32 + b)) * 256 + t * 128 + col] = v;
        else                C[((size_t)row * 64 + p) * 128 + col] = v;
      }
}

// ---------------------------------------------------------------------------
// inv_kernel: per (pair, k-block) compute M = (I + L_diag)^{-1} (unit lower
// 32x32) by forward substitution on identity columns; store as pre-swizzled
// bf16 hi/lo MFMA A-fragments: Mg[(pk*2+rowtile)*64 + lane] = 8 bf16 (16B).
// 512 blocks x 64 threads, massively parallel.
// ---------------------------------------------------------------------------
__global__ __launch_bounds__(64) void inv_kernel(
    const float* __restrict__ L,   // [64][256][256] strict-lower
    u16* __restrict__ MgH, u16* __restrict__ MgL) {
  const int pk = blockIdx.x;
  const int p = pk >> 3, s0 = (pk & 7) * 32;
  const int lane = threadIdx.x;
  __shared__ float Db[32][33];
  __shared__ float Ms[32][33];
  const float* Lp = L + (size_t)p * 65536;
  {
    const int r = lane >> 1, c0 = (lane & 1) * 16;
    const float* src = Lp + (size_t)(s0 + r) * 256 + s0 + c0;
    float4 v0 = ((const float4*)src)[0], v1 = ((const float4*)src)[1];
    float4 v2 = ((const float4*)src)[2], v3 = ((const float4*)src)[3];
    *(float4*)&Db[r][c0]      = v0; *(float4*)&Db[r][c0 + 4]  = v1;
    *(float4*)&Db[r][c0 + 8]  = v2; *(float4*)&Db[r][c0 + 12] = v3;
  }
  __syncthreads();
  if (lane < 32) {
    const int j = lane;
    float m[32];
#pragma unroll
    for (int r = 0; r < 32; ++r) {
      float xa = (r == j) ? 1.f : 0.f;
      float xb = 0.f;
#pragma unroll
      for (int q = 0; q < 32; ++q) {
        if (q < r) {
          if (q & 1) xb -= Db[r][q] * m[q];
          else       xa -= Db[r][q] * m[q];
        }
      }
      float x = xa + xb;
      m[r] = x;
      Ms[r][j] = x;
    }
  }
  __syncthreads();
  const int l15 = lane & 15, l4 = lane >> 4;
#pragma unroll
  for (int rt = 0; rt < 2; ++rt) {
    u32 wh[4], wl[4];
#pragma unroll
    for (int i2 = 0; i2 < 4; ++i2) {
      float v0 = Ms[rt * 16 + l15][l4 * 8 + i2 * 2];
      float v1 = Ms[rt * 16 + l15][l4 * 8 + i2 * 2 + 1];
      u16 h0 = f2bf(v0), h1 = f2bf(v1);
      u16 g0 = f2bf(v0 - bf2f(h0)), g1 = f2bf(v1 - bf2f(h1));
      wh[i2] = (u32)h0 | ((u32)h1 << 16);
      wl[i2] = (u32)g0 | ((u32)g1 << 16);
    }
    size_t off = (((size_t)pk * 2 + rt) * 64 + lane) * 8;
    *(uint4*)(MgH + off) = make_uint4(wh[0], wh[1], wh[2], wh[3]);
    *(uint4*)(MgL + off) = make_uint4(wl[0], wl[1], wl[2], wl[3]);
  }
}

// ---------------------------------------------------------------------------
// MFMA blocked triangular solve. Grid 128 = (pair, half); 4 waves; wave w
// owns rhs columns w*16..w*16+15 (its slices of dBs/accT are wave-private ->
// only 2 barriers per phase, around the cooperative -L staging).
// Phase k: acc = b_k + (-L)@delta_{<k} (MFMA, 3-term bf16 compensation),
// delta_k = M_k @ acc (MFMA, M from inv_kernel). delta kept in LDS as bf16
// hi/lo B-fragments [col][K]; f32 result written to global.
// r9 was LDS-port-bound (4 waves x b128 VALU dot-products ~100K cyc) + a
// wave0-only 32-deep serial phase; this removes both.
// ---------------------------------------------------------------------------
__global__ __launch_bounds__(256, 1) void solve_kernel(
    const float* __restrict__ L,        // [64][256][256] strict-lower, rw1-scaled
    const u16* __restrict__ values,     // bf16 [8192][256]
    const float* __restrict__ pc,       // [64][256][8]
    const u16* __restrict__ MgH, const u16* __restrict__ MgL,
    float* __restrict__ delta) {        // [64][256][128]
  const int p = blockIdx.x >> 1, hf = blockIdx.x & 1;
  const int b = p >> 1, t = p & 1;
  const int tid = threadIdx.x, w = tid >> 6, lane = tid & 63;
  const int l15 = lane & 15, l4 = lane >> 4;
  const int col = w * 16 + l15;   // rhs column (wave-private 16-col slice)
  __shared__ u16 dBsH[64][264];   // delta^T bf16-hi  [col][K]
  __shared__ u16 dBsL[64][264];   // delta^T bf16-lo
  __shared__ u16 Lh[32][264];     // -L row-block bf16-hi [row][col<s0]
  __shared__ u16 Ll[32][264];
  __shared__ u16 accTH[64][40];   // rhs^T bf16-hi [col][K=32]
  __shared__ u16 accTL[64][40];
  const float* Lp = L + (size_t)p * 65536;
  const int srow = tid >> 3, sseg = tid & 7;

  for (int k = 0; k < 8; ++k) {
    const int s0 = k * 32;
    // ---- b_k into MFMA C layout (rowtiles 0/1) ----
    f32x4 acc0 = {}, acc1 = {};
#pragma unroll
    for (int r = 0; r < 4; ++r) {
      int s = s0 + l4 * 4 + r;
      float rv = bf2f(values[((size_t)(s * 32 + b)) * 256 + t * 128 + hf * 64 + col]);
      acc0[r] = rv * pc[((size_t)p * 256 + s) * 8 + 7];
      int s2 = s + 16;
      float rv2 = bf2f(values[((size_t)(s2 * 32 + b)) * 256 + t * 128 + hf * 64 + col]);
      acc1[r] = rv2 * pc[((size_t)p * 256 + s2) * 8 + 7];
    }
    // ---- prefetch M_k A-fragments from global (coalesced by lane) ----
    size_t mo0 = (((size_t)(p * 8 + k) * 2 + 0) * 64 + lane) * 8;
    size_t mo1 = (((size_t)(p * 8 + k) * 2 + 1) * 64 + lane) * 8;
    s16x8 mh0 = *(const s16x8*)(MgH + mo0);
    s16x8 mh1 = *(const s16x8*)(MgH + mo1);
    s16x8 ml0 = *(const s16x8*)(MgL + mo0);
    s16x8 ml1 = *(const s16x8*)(MgL + mo1);
    // ---- cooperative stage of -L rows [s0,s0+32) cols [0,s0) as bf16 hi/lo
    for (int c4 = sseg; c4 * 4 < s0; c4 += 8) {
      float4 lv = *(const float4*)(Lp + (size_t)(s0 + srow) * 256 + c4 * 4);
      float x0 = -lv.x, x1 = -lv.y, x2 = -lv.z, x3 = -lv.w;
      u16 h0 = f2bf(x0), h1 = f2bf(x1), h2 = f2bf(x2), h3 = f2bf(x3);
      u16 g0 = f2bf(x0 - bf2f(h0)), g1 = f2bf(x1 - bf2f(h1));
      u16 g2 = f2bf(x2 - bf2f(h2)), g3 = f2bf(x3 - bf2f(h3));
      *(uint2*)&Lh[srow][c4 * 4] = make_uint2((u32)h0 | ((u32)h1 << 16), (u32)h2 | ((u32)h3 << 16));
      *(uint2*)&Ll[srow][c4 * 4] = make_uint2((u32)g0 | ((u32)g1 << 16), (u32)g2 | ((u32)g3 << 16));
    }
    __syncthreads();   // Lh/Ll staged; prior phase's dBs writes visible
    // ---- stage 1: acc += (-L) @ delta  over 32-col chunks ----
    for (int m = 0; m < k; ++m) {
      s16x8 bh = *(const s16x8*)&dBsH[col][m * 32 + l4 * 8];
      s16x8 bl = *(const s16x8*)&dBsL[col][m * 32 + l4 * 8];
      s16x8 a0h = *(const s16x8*)&Lh[l15][m * 32 + l4 * 8];
      s16x8 a0l = *(const s16x8*)&Ll[l15][m * 32 + l4 * 8];
      s16x8 a1h = *(const s16x8*)&Lh[16 + l15][m * 32 + l4 * 8];
      s16x8 a1l = *(const s16x8*)&Ll[16 + l15][m * 32 + l4 * 8];
      acc0 = __builtin_amdgcn_mfma_f32_16x16x32_bf16(a0h, bh, acc0, 0, 0, 0);
      acc0 = __builtin_amdgcn_mfma_f32_16x16x32_bf16(a0h, bl, acc0, 0, 0, 0);
      acc0 = __builtin_amdgcn_mfma_f32_16x16x32_bf16(a0l, bh, acc0, 0, 0, 0);
      acc1 = __builtin_amdgcn_mfma_f32_16x16x32_bf16(a1h, bh, acc1, 0, 0, 0);
      acc1 = __builtin_amdgcn_mfma_f32_16x16x32_bf16(a1h, bl, acc1, 0, 0, 0);
      acc1 = __builtin_amdgcn_mfma_f32_16x16x32_bf16(a1l, bh, acc1, 0, 0, 0);
    }
    // ---- transpose acc -> accT (wave-private; C layout row = l4*4+r) ----
    {
      u16 th[8], tl[8];
#pragma unroll
      for (int r = 0; r < 4; ++r) {
        u16 h = f2bf(acc0[r]); th[r] = h; tl[r] = f2bf(acc0[r] - bf2f(h));
        u16 h2 = f2bf(acc1[r]); th[4 + r] = h2; tl[4 + r] = f2bf(acc1[r] - bf2f(h2));
      }
      *(uint2*)&accTH[col][l4 * 4]      = make_uint2((u32)th[0] | ((u32)th[1] << 16), (u32)th[2] | ((u32)th[3] << 16));
      *(uint2*)&accTH[col][16 + l4 * 4] = make_uint2((u32)th[4] | ((u32)th[5] << 16), (u32)th[6] | ((u32)th[7] << 16));
      *(uint2*)&accTL[col][l4 * 4]      = make_uint2((u32)tl[0] | ((u32)tl[1] << 16), (u32)tl[2] | ((u32)tl[3] << 16));
      *(uint2*)&accTL[col][16 + l4 * 4] = make_uint2((u32)tl[4] | ((u32)tl[5] << 16), (u32)tl[6] | ((u32)tl[7] << 16));
    }
    // ---- stage 2: delta_k = M_k @ acc (wave-private accT read) ----
    f32x4 d0 = {}, d1 = {};
    {
      s16x8 bh = *(const s16x8*)&accTH[col][l4 * 8];
      s16x8 bl = *(const s16x8*)&accTL[col][l4 * 8];
      d0 = __builtin_amdgcn_mfma_f32_16x16x32_bf16(mh0, bh, d0, 0, 0, 0);
      d0 = __builtin_amdgcn_mfma_f32_16x16x32_bf16(mh0, bl, d0, 0, 0, 0);
      d0 = __builtin_amdgcn_mfma_f32_16x16x32_bf16(ml0, bh, d0, 0, 0, 0);
      d1 = __builtin_amdgcn_mfma_f32_16x16x32_bf16(mh1, bh, d1, 0, 0, 0);
      d1 = __builtin_amdgcn_mfma_f32_16x16x32_bf16(mh1, bl, d1, 0, 0, 0);
      d1 = __builtin_amdgcn_mfma_f32_16x16x32_bf16(ml1, bh, d1, 0, 0, 0);
    }
    // ---- write delta f32 (global) + bf16 hi/lo into dBs (wave-private) ----
#pragma unroll
    for (int r = 0; r < 4; ++r) {
      int row0 = l4 * 4 + r;
      delta[((size_t)p * 256 + s0 + row0) * 128 + hf * 64 + col] = d0[r];
      delta[((size_t)p * 256 + s0 + 16 + row0) * 128 + hf * 64 + col] = d1[r];
    }
    {
      u16 dh[8], dl[8];
#pragma unroll
      for (int r = 0; r < 4; ++r) {
        u16 h = f2bf(d0[r]); dh[r] = h; dl[r] = f2bf(d0[r] - bf2f(h));
        u16 h2 = f2bf(d1[r]); dh[4 + r] = h2; dl[4 + r] = f2bf(d1[r] - bf2f(h2));
      }
      *(uint2*)&dBsH[col][s0 + l4 * 4]      = make_uint2((u32)dh[0] | ((u32)dh[1] << 16), (u32)dh[2] | ((u32)dh[3] << 16));
      *(uint2*)&dBsH[col][s0 + 16 + l4 * 4] = make_uint2((u32)dh[4] | ((u32)dh[5] << 16), (u32)dh[6] | ((u32)dh[7] << 16));
      *(uint2*)&dBsL[col][s0 + l4 * 4]      = make_uint2((u32)dl[0] | ((u32)dl[1] << 16), (u32)dl[2] | ((u32)dl[3] << 16));
      *(uint2*)&dBsL[col][s0 + 16 + l4 * 4] = make_uint2((u32)dl[4] | ((u32)dl[5] << 16), (u32)dl[6] | ((u32)dl[7] << 16));
    }
    __syncthreads();   // protect Lh/Ll from next phase's restaging
  }
}

// ---------------------------------------------------------------------------
extern "C" void kernel_launch(void* const* d_in, const int* in_sizes, int n_in,
                              void* d_out, int out_size, void* d_ws, size_t ws_size,
                              hipStream_t stream) {
  const float* inputs = (const float*)d_in[0];
  const float* W_ih = (const float*)d_in[2];
  const float* W_hh = (const float*)d_in[3];
  const float* b_ih = (const float*)d_in[4];
  const float* b_hh = (const float*)d_in[5];
  const float* W_val = (const float*)d_in[6];
  const float* b_val = (const float*)d_in[7];
  const float* W_out = (const float*)d_in[8];
  const float* b_out = (const float*)d_in[9];

  float* out = (float*)d_out;
  float* out_tape = out + 2097152;
  float* out_rpos = out + 4194304;
  float* out_wpos = out + 4210688;

  char* ws = (char*)d_ws;
  float* posW      = (float*)(ws);                    // 16 MB  [64][256][256]
  float* posRs     = (float*)(ws + 16777216);         // 16 MB  (reused: reads_f32)
  float* LHm       = (float*)(ws + 33554432);         // 16 MB  (L, then Hm)
  u16*   values_bf = (u16*)  (ws + 50331648);         //  4 MB
  float* xg        = (float*)(ws + 54525952);         //  2 MB (dead after lstm)
  float* delta     = (float*)(ws + 54525952);         //  8 MB (aliases xg)
  float* pcb       = (float*)(ws + 62914560);         // 512 KB [64][256][8]
  float* hout      = (float*)(ws + 63438848);         // 512 KB [256][32][16]
  u16*   MgH       = (u16*)  (ws + 63963136);         //  1 MB M frags hi
  u16*   MgL       = (u16*)  (ws + 65011712);         //  1 MB M frags lo (end ~63 MiB)
  float* reads_f32 = posRs;

  // 1. values (bf16) = inputs @ W_val^T + b_val
  gemm_mfma<false, true><<<dim3(64, 4), 256, 0, stream>>>(inputs, W_val, b_val, values_bf, 256);
  // 2. xg (f32) = inputs @ W_ih^T + (b_ih + b_hh)
  gemm_nt<<<dim3(128, 1), 256, 0, stream>>>(inputs, W_ih, b_ih, b_hh, xg, 64);
  // 3. LSTM core -> raw h
  lstm_kernel<<<32, 64, 0, stream>>>(xg, W_hh, hout);
  // 3b. action heads -> packed coefficients pc
  head_kernel<<<512, 256, 0, stream>>>(hout, pcb);
  // 4. position trajectories
  pos_kernel<<<64, 64, 0, stream>>>(pcb, posW, posRs, out_rpos, out_wpos);
  // 5. L = rw1 (.) strict_tril(posW posW^T)
  bgemm<false, true, 1, 0, 256><<<dim3(4, 2, 64), 256, 0, stream>>>(
      posW, posW, pcb, LHm, 65536, 65536);
  // 5b. diag-block inverses M_k (bf16 hi/lo A-fragments)
  inv_kernel<<<512, 64, 0, stream>>>(LHm, MgH, MgL);
  // 6. MFMA blocked triangular solve -> delta
  solve_kernel<<<128, 256, 0, stream>>>(LHm, values_bf, pcb, MgH, MgL, delta);
  // 7. Hm = tril_incl(posRs posW^T)   (overwrites L)
  bgemm<false, true, 2, 0, 256><<<dim3(4, 2, 64), 256, 0, stream>>>(
      posRs, posW, pcb, LHm, 65536, 65536);
  // 8. reads = Hm @ delta   (reads layout [s*32+b][256])
  bgemm<false, false, 0, 1, 128><<<dim3(2, 2, 64), 256, 0, stream>>>(
      LHm, delta, pcb, reads_f32, 65536, 32768);
  // 9. out_tape = posW^T @ delta
  bgemm<true, false, 0, 2, 128><<<dim3(2, 2, 64), 256, 0, stream>>>(
      posW, delta, pcb, out_tape, 65536, 32768);
  // 10. outputs = reads @ W_out^T + b_out
  gemm_mfma<false, false><<<dim3(64, 4), 256, 0, stream>>>(reads_f32, W_out, b_out, out, 256);
}